// Round 8
// baseline (166.682 us; speedup 1.0000x reference)
//
#include <hip/hip_runtime.h>
#include <hip/hip_cooperative_groups.h>
#include <math.h>

#define POOL 7
#define NUM_ROIS 300
#define FH 50
#define FW 50
#define FC 512
#define NBINS (POOL * POOL)                    // 49 bins per ROI
#define FMAX_N (FH * FW)                       // 2500 pixels
#define ROW_F4 (POOL * FC / 4)                 // 896 float4 per (roi,row-bin)
#define NTASK (NUM_ROIS * POOL)                // 2100 (roi,row-bin) tasks
#define GRID 2048                              // max co-resident: 8 blk/CU x 256 CU

typedef float floatx4 __attribute__((ext_vector_type(4)));  // native vec for nontemporal

// Single cooperative launch, NO redundant work (unlike R4/R7 fusions):
// Phase 1: global wave w (0..2499 of 8192) reduces pixel w's 512 channels
//          (fmax computed exactly once, as in the 2-launch K1).
// grid.sync()
// Phase 2: R6's balanced per-(roi,row-bin) pooling: lanes 0..6 compute the
//          7 col-bins from the 10 KB L2-hot fmax_g, then 896 nontemporal
//          float4 stores. Grid-stride (tasks 0..2099 over 2048 blocks).
__global__ __launch_bounds__(256) void roi_pool_coop(
    const float* __restrict__ rois, const float* __restrict__ fm,
    float* __restrict__ out, float* __restrict__ fmax_g) {
    __shared__ float pooled[POOL];
    int t = threadIdx.x;
    int lane = t & 63;

    // ---- Phase 1: channel-max, one wave per pixel ----
    int gw = (blockIdx.x << 2) + (t >> 6);      // global wave id, 0..8191
    if (gw < FMAX_N) {
        const float4* p = (const float4*)(fm + (size_t)gw * FC);
        float4 a = p[lane];
        float4 b = p[lane + 64];
        float m = fmaxf(fmaxf(fmaxf(a.x, a.y), fmaxf(a.z, a.w)),
                        fmaxf(fmaxf(b.x, b.y), fmaxf(b.z, b.w)));
        #pragma unroll
        for (int off = 32; off > 0; off >>= 1)
            m = fmaxf(m, __shfl_down(m, off, 64));
        if (lane == 0) fmax_g[gw] = m;
    }

    cooperative_groups::this_grid().sync();

    // ---- Phase 2: pool + broadcast write, one task per block (+tail) ----
    for (int task = blockIdx.x; task < NTASK; task += GRID) {
        int n = task / POOL;                    // roi
        int i = task - n * POOL;                // row bin

        if (t < POOL) {
            int j = t;                          // col bin (one per lane)

            // Replicate: r = int32(roi * (1/16)) (trunc; values non-negative).
            int x1 = (int)(rois[n * 5 + 1] * 0.0625f);
            int y1 = (int)(rois[n * 5 + 2] * 0.0625f);
            int x2 = (int)(rois[n * 5 + 3] * 0.0625f);
            int y2 = (int)(rois[n * 5 + 4] * 0.0625f);
            int rh = y2 - y1 + 1;
            int rw = x2 - x1 + 1;

            // Python floor-div on non-negative ints == C int division here.
            int hs = min(max(y1 + (i * rh) / POOL, 0), FH);
            int he = min(max(y1 + ((i + 1) * rh + POOL - 1) / POOL, 0), FH);
            int ws = min(max(x1 + (j * rw) / POOL, 0), FW);
            int we = min(max(x1 + ((j + 1) * rw + POOL - 1) / POOL, 0), FW);

            float m = -INFINITY;                // empty bin -> -inf (matches ref)
            for (int h = hs; h < he; ++h)
                for (int w = ws; w < we; ++w)
                    m = fmaxf(m, fmax_g[h * FW + w]);
            pooled[t] = m;
        }
        __syncthreads();

        // 7*512 floats = 896 float4 for this (roi,row-bin); col bin = f >> 7.
        floatx4* o4 =
            (floatx4*)(out + ((size_t)n * NBINS + (size_t)i * POOL) * FC);
        for (int f = t; f < ROW_F4; f += 256) {
            float m = pooled[f >> 7];
            floatx4 v = {m, m, m, m};
            __builtin_nontemporal_store(v, &o4[f]);
        }
        __syncthreads();                        // protect pooled[] for tail task
    }
}

extern "C" void kernel_launch(void* const* d_in, const int* in_sizes, int n_in,
                              void* d_out, int out_size, void* d_ws, size_t ws_size,
                              hipStream_t stream) {
    const float* rois = (const float*)d_in[0];          // (300, 5) f32
    const float* feature_maps = (const float*)d_in[1];  // (50, 50, 512) f32
    float* out = (float*)d_out;                         // (300, 7, 7, 512) f32
    float* fmax_g = (float*)d_ws;                       // 2500 floats (ws is free)

    void* args[] = {(void*)&rois, (void*)&feature_maps, (void*)&out,
                    (void*)&fmax_g};
    hipLaunchCooperativeKernel((const void*)roi_pool_coop, dim3(GRID),
                               dim3(256), args, 0, stream);
}

// Round 10
// 69.922 us; speedup vs baseline: 2.3838x; 2.3838x over previous
//
#include <hip/hip_runtime.h>
#include <math.h>

#define POOL 7
#define NUM_ROIS 300
#define FH 50
#define FW 50
#define FC 512
#define NBINS (POOL * POOL)                    // 49 bins per ROI
#define FMAX_N (FH * FW)                       // 2500 pixels
#define ROW_F4 (POOL * FC / 4)                 // 896 float4 per (roi,row-bin)

typedef float floatx4 __attribute__((ext_vector_type(4)));  // native vec for nontemporal

// K1: fmax[h][w] = max over C of feature_maps[h][w][c]
// 256-thread blocks, one wave per pixel (4 pixels/block) -> 625 workgroups, ~2 us.
__global__ __launch_bounds__(256) void channel_max_kernel(
    const float* __restrict__ fm, float* __restrict__ fmax_g) {
    int wave = threadIdx.x >> 6;
    int lane = threadIdx.x & 63;
    int pix = blockIdx.x * 4 + wave;            // 0..2499
    const float4* p = (const float4*)(fm + (size_t)pix * FC);
    float4 a = p[lane];
    float4 b = p[lane + 64];
    float m = fmaxf(fmaxf(fmaxf(a.x, a.y), fmaxf(a.z, a.w)),
                    fmaxf(fmaxf(b.x, b.y), fmaxf(b.z, b.w)));
    #pragma unroll
    for (int off = 32; off > 0; off >>= 1)
        m = fmaxf(m, __shfl_down(m, off, 64));
    if (lane == 0) fmax_g[pix] = m;
}

// K2: one block per (roi, row-bin): 2100 blocks x 256 threads (~8.2/CU).
// Lanes 0..6 compute the 7 col-bin maxima straight from fmax_g (10 KB,
// L1/L2-resident; <=64 loads each, avg ~9). One LDS[7] + one barrier, then
// 896 balanced nontemporal float4 stores (30 MB aggregate = output floor).
__global__ __launch_bounds__(256) void pool_row_kernel(
    const float* __restrict__ rois, const float* __restrict__ fmax_g,
    float* __restrict__ out) {
    __shared__ float pooled[POOL];
    int b = blockIdx.x;
    int n = b / POOL;                           // roi
    int i = b - n * POOL;                       // row bin
    int t = threadIdx.x;

    if (t < POOL) {
        int j = t;                              // col bin (one per lane)

        // Replicate: r = int32(roi * (1/16)) (truncation; values non-negative).
        int x1 = (int)(rois[n * 5 + 1] * 0.0625f);
        int y1 = (int)(rois[n * 5 + 2] * 0.0625f);
        int x2 = (int)(rois[n * 5 + 3] * 0.0625f);
        int y2 = (int)(rois[n * 5 + 4] * 0.0625f);
        int rh = y2 - y1 + 1;
        int rw = x2 - x1 + 1;

        // Python floor-div on non-negative ints == C int division here.
        int hs = min(max(y1 + (i * rh) / POOL, 0), FH);
        int he = min(max(y1 + ((i + 1) * rh + POOL - 1) / POOL, 0), FH);
        int ws = min(max(x1 + (j * rw) / POOL, 0), FW);
        int we = min(max(x1 + ((j + 1) * rw + POOL - 1) / POOL, 0), FW);

        float m = -INFINITY;                    // empty bin -> -inf (matches ref)
        for (int h = hs; h < he; ++h)
            for (int w = ws; w < we; ++w)
                m = fmaxf(m, fmax_g[h * FW + w]);
        pooled[t] = m;
    }
    __syncthreads();

    // Write this (roi,row-bin)'s 7*512 floats = 896 float4; col bin = f >> 7.
    floatx4* o4 = (floatx4*)(out + ((size_t)n * NBINS + (size_t)i * POOL) * FC);
    for (int f = t; f < ROW_F4; f += 256) {
        float m = pooled[f >> 7];
        floatx4 v = {m, m, m, m};
        __builtin_nontemporal_store(v, &o4[f]);
    }
}

extern "C" void kernel_launch(void* const* d_in, const int* in_sizes, int n_in,
                              void* d_out, int out_size, void* d_ws, size_t ws_size,
                              hipStream_t stream) {
    const float* rois = (const float*)d_in[0];          // (300, 5) f32
    const float* feature_maps = (const float*)d_in[1];  // (50, 50, 512) f32
    float* out = (float*)d_out;                         // (300, 7, 7, 512) f32
    float* fmax_g = (float*)d_ws;                       // 2500 floats

    channel_max_kernel<<<FMAX_N / 4, 256, 0, stream>>>(feature_maps, fmax_g);
    pool_row_kernel<<<NUM_ROIS * POOL, 256, 0, stream>>>(rois, fmax_g, out);
}